// Round 6
// baseline (714.392 us; speedup 1.0000x reference)
//
#include <hip/hip_runtime.h>
#include <stdint.h>

typedef unsigned long long u64;
typedef float v2 __attribute__((ext_vector_type(2)));

#define THRESH_F 5e-5f
#define BB 128
#define HH 384
#define WW_ 384
#define WPR 6                        // u64 words per 384-pixel row
#define IMG_WORDS (HH*WPR)           // 2304
#define OH 378
#define OW 378
#define PIX (BB*HH*WW_)              // 18874368
#define COVN (49.0f/48.0f)

#define SLAB 48                      // output rows per morph block
#define HALO 30                      // morphology chain depth: 1 + 15 + 14
#define MAXROWS (SLAB + 2*HALO)      // 108
#define MAXW (MAXROWS * WPR)         // 648

#define BIN_BLOCKS 1536

// div by 6 via magic, valid for w < 131072
__device__ __forceinline__ int div6(int w) { return (w * 43691) >> 18; }

// ---- K1: binarize Y -> bits. MLP=8: 8 loads + 8 ballots per step ----------
// lane loads elems base+{0..7}*64+lane; 8 ballots give 8 u64 words; lanes
// 0..7 store them contiguously (64B). 6 grid-stride steps, 2KB/wave in
// flight to cover ~900cyc HBM latency.
__global__ void __launch_bounds__(256) k_binarize(const float* __restrict__ Y,
                                                  u64* __restrict__ bits,
                                                  float* __restrict__ accum) {
    if (blockIdx.x == 0) {           // zero accum bins (consumed by k_ssim)
        for (int i = threadIdx.x; i < 1024; i += 256) accum[i] = 0.f;
    }
    const int lane = threadIdx.x & 63;
    const int wave = (blockIdx.x * 256 + threadIdx.x) >> 6;   // global wave id
    const int nwaves = BIN_BLOCKS * 4;                        // 6144
    const int NSTEP = PIX / 512;                              // 36864
    for (int s = wave; s < NSTEP; s += nwaves) {
        size_t base = (size_t)s * 512 + lane;
        float a0 = Y[base];
        float a1 = Y[base + 64];
        float a2 = Y[base + 128];
        float a3 = Y[base + 192];
        float a4 = Y[base + 256];
        float a5 = Y[base + 320];
        float a6 = Y[base + 384];
        float a7 = Y[base + 448];
        u64 b0 = __ballot(a0 > THRESH_F);
        u64 b1 = __ballot(a1 > THRESH_F);
        u64 b2 = __ballot(a2 > THRESH_F);
        u64 b3 = __ballot(a3 > THRESH_F);
        u64 b4 = __ballot(a4 > THRESH_F);
        u64 b5 = __ballot(a5 > THRESH_F);
        u64 b6 = __ballot(a6 > THRESH_F);
        u64 b7 = __ballot(a7 > THRESH_F);
        if (lane < 8) {
            u64 lo = (lane == 0) ? b0 : (lane == 1) ? b1 : (lane == 2) ? b2 : b3;
            u64 hi = (lane == 4) ? b4 : (lane == 5) ? b5 : (lane == 6) ? b6 : b7;
            bits[(size_t)s * 8 + lane] = (lane < 4) ? lo : hi;
        }
    }
}

// ---- K2: fused morphology on bits, 8 slabs per image (1024 blocks) --------
__global__ void __launch_bounds__(256) k_morph(const u64* __restrict__ gbits,
                                               u64* __restrict__ gout_all) {
    __shared__ u64 A[MAXW];
    __shared__ u64 Bf[MAXW];
    const int blk = blockIdx.x;
    const int b = blk >> 3;
    const int slab = blk & 7;
    const int r0 = slab * SLAB;
    const int w0row = (r0 - HALO < 0) ? 0 : r0 - HALO;
    int w1row = r0 + SLAB + HALO; if (w1row > HH) w1row = HH;
    const int nrows = w1row - w0row;                  // 78 or 108
    const int NW = nrows * WPR;
    const int t = threadIdx.x;

    const u64* gin = gbits + (size_t)b * IMG_WORDS + (size_t)w0row * WPR;
    for (int w = t; w < NW; w += 256) A[w] = gin[w];
    __syncthreads();

    // ---- erode3: A -> Bf ----
    for (int w = t; w < NW; w += 256) {
        int row = div6(w);
        int ww = w - row * 6;
        int rlo = row > 0 ? row - 1 : row;
        int rhi = row < nrows - 1 ? row + 1 : row;
        u64 res = ~0ull;
        for (int rr = rlo; rr <= rhi; ++rr) {
            const u64* rp = &A[rr * 6];
            u64 a = ww > 0 ? rp[ww - 1] : 0ull;
            u64 bb = rp[ww];
            u64 c = ww < 5 ? rp[ww + 1] : 0ull;
            u64 l  = (bb << 1) | (ww > 0 ? (a >> 63) : 1ull);
            u64 r2 = (bb >> 1) | (ww < 5 ? (c << 63) : (1ull << 63));
            res &= bb & l & r2;
        }
        Bf[w] = res;
    }
    __syncthreads();

    // ---- dilate_h15: Bf -> A ----
    for (int w = t; w < NW; w += 256) {
        int row = div6(w);
        int ww = w - row * 6;
        const u64* rp = &Bf[row * 6];
        u64 a = ww > 0 ? rp[ww - 1] : 0ull;
        u64 bb = rp[ww];
        u64 c = ww < 5 ? rp[ww + 1] : 0ull;
        __uint128_t X = (((__uint128_t)bb) << 64) | a;
        X |= X << 1; X |= X << 2; X |= X << 4; X |= X << 8;
        __uint128_t Z = (((__uint128_t)c) << 64) | bb;
        Z |= Z >> 1; Z |= Z >> 2; Z |= Z >> 4; Z |= Z >> 8;
        A[w] = (u64)(X >> 64) | (u64)Z;
    }
    __syncthreads();

    // ---- dilate_v15: A -> Bf ----
    for (int w = t; w < NW; w += 256) {
        int row = div6(w);
        int ww = w - row * 6;
        int lo2 = row - 15 < 0 ? 0 : row - 15;
        int hi2 = row + 15 > nrows - 1 ? nrows - 1 : row + 15;
        u64 acc = 0ull;
        for (int rr = lo2; rr <= hi2; ++rr) acc |= A[rr * 6 + ww];
        Bf[w] = acc;
    }
    __syncthreads();

    // ---- erode_h14: Bf -> A ----
    for (int w = t; w < NW; w += 256) {
        int row = div6(w);
        int ww = w - row * 6;
        const u64* rp = &Bf[row * 6];
        u64 a = ww > 0 ? rp[ww - 1] : ~0ull;
        u64 bb = rp[ww];
        u64 c = ww < 5 ? rp[ww + 1] : ~0ull;
        u64 na = ~a, nb = ~bb, nc = ~c;
        __uint128_t X = (((__uint128_t)nb) << 64) | na;
        X |= X << 1; X |= X << 2; X |= X << 4; X |= X << 7;
        __uint128_t Z = (((__uint128_t)nc) << 64) | nb;
        Z |= Z >> 1; Z |= Z >> 2; Z |= Z >> 4; Z |= Z >> 7;
        A[w] = ~((u64)(X >> 64) | (u64)Z);
    }
    __syncthreads();

    // ---- erode_v14: A -> global, output rows [r0, r0+48) ----
    u64* gout = gout_all + (size_t)b * IMG_WORDS;
    const int base = r0 - w0row;
    for (int w = t; w < SLAB * WPR; w += 256) {
        int lrow = div6(w);
        int ww = w - lrow * 6;
        int lr = base + lrow;
        int lo2 = lr - 14 < 0 ? 0 : lr - 14;
        int hi2 = lr + 14 > nrows - 1 ? nrows - 1 : lr + 14;
        u64 acc = ~0ull;
        for (int rr = lo2; rr <= hi2; ++rr) acc &= A[rr * 6 + ww];
        gout[(size_t)(r0 + lrow) * WPR + ww] = acc;
    }
}

// ---- K3: masked SSIM, CW=2, chunk=27, DEPTH-2 row pipeline ----------------
// grid (3, 7, 128), block 128. R1/R4-proven body (69 us @ VGPR 112 = 4
// waves/SIMD). __launch_bounds__(128, 5) asks the allocator for <=102 VGPR
// -> 5 waves/SIMD (+25% TLP against the ~48% latency-stall fraction).
// No finalize fusion (R3/R5 both regressed); plain bin atomicAdd tail.
__global__ void __launch_bounds__(128, 5) k_ssim(
    const float* __restrict__ Xg, const float* __restrict__ Yg,
    const float* __restrict__ drg, const u64* __restrict__ Mg,
    float* __restrict__ accum)
{
    const int tx = threadIdx.x & 63;
    const int cz = threadIdx.x >> 6;                  // 0..1
    const int p  = blockIdx.x * 64 + tx;              // pair index
    const int chunk = blockIdx.y * 2 + cz;            // 0..13
    const int b  = blockIdx.z;

    float lsum = 0.0f;
    if (p < 189) {
        const int j  = p * 2;
        const int i0 = chunk * 27;                    // 378 = 14*27 exact
        const float drv = drg[b];
        const float C1q = 1e-4f * drv * drv * 2401.0f;    // C1*49^2
        const float C2q = 9e-4f * drv * drv * 2401.0f;    // C2*49^2
        const float* xr = Xg + (size_t)b * HH * WW_ + (size_t)i0 * WW_ + j;
        const float* yr = Yg + (size_t)b * HH * WW_ + (size_t)i0 * WW_ + j;
        const unsigned* mr = (const unsigned*)Mg + ((size_t)b * HH + i0) * 12 + (j >> 5);
        const int sh32 = j & 31;

        v2 r0[7], r1[7], r2[7], r3[7], r4[7];
        #pragma unroll
        for (int t = 0; t < 7; ++t) {
            r0[t] = 0.f; r1[t] = 0.f; r2[t] = 0.f; r3[t] = 0.f; r4[t] = 0.f;
        }
        v2 s0 = 0.f, s1 = 0.f, s2 = 0.f, s3 = 0.f, s4 = 0.f;

        // pipeline stage A (row rr), stage B (row rr+1)
        v2 ax0 = *(const v2*)(xr),     ax1 = *(const v2*)(xr + 2);
        v2 ax2 = *(const v2*)(xr + 4), ax3 = *(const v2*)(xr + 6);
        v2 ay0 = *(const v2*)(yr),     ay1 = *(const v2*)(yr + 2);
        v2 ay2 = *(const v2*)(yr + 4), ay3 = *(const v2*)(yr + 6);
        unsigned am0 = mr[0], am1 = mr[1];

        const float* xn1 = xr + WW_;
        const float* yn1 = yr + WW_;
        v2 bx0 = *(const v2*)(xn1),     bx1 = *(const v2*)(xn1 + 2);
        v2 bx2 = *(const v2*)(xn1 + 4), bx3 = *(const v2*)(xn1 + 6);
        v2 by0 = *(const v2*)(yn1),     by1 = *(const v2*)(yn1 + 2);
        v2 by2 = *(const v2*)(yn1 + 4), by3 = *(const v2*)(yn1 + 6);
        unsigned bm0 = mr[12], bm1 = mr[13];

        for (int bs = 0; bs < 35; bs += 7) {
            #pragma unroll
            for (int ph = 0; ph < 7; ++ph) {
                const int rr = bs + ph;
                if (rr >= 33) break;                  // uniform

                // ---- prefetch row min(rr+2, 32): unconditional, clamped ----
                int rp = rr + 2; if (rp > 32) rp = 32;
                const float* xn = xr + (size_t)rp * WW_;
                const float* yn = yr + (size_t)rp * WW_;
                v2 tx0 = *(const v2*)(xn),     tx1 = *(const v2*)(xn + 2);
                v2 tx2 = *(const v2*)(xn + 4), tx3 = *(const v2*)(xn + 6);
                v2 ty0 = *(const v2*)(yn),     ty1 = *(const v2*)(yn + 2);
                v2 ty2 = *(const v2*)(yn + 4), ty3 = *(const v2*)(yn + 6);
                const unsigned* mn = mr + (size_t)rp * 12;
                unsigned tm0 = mn[0], tm1 = mn[1];

                // ---- compute row rr from stage A ----
                unsigned win8 = __builtin_amdgcn_alignbit(am1, am0, sh32) & 0xFFu;
                v2 xa = ax0, xb = ax1, xc = ax2, xd = ax3;
                v2 ya = ay0, yb = ay1, yc = ay2, yd = ay3;

                if (__builtin_expect(__any(win8 != 0xFFu), 0)) {
                    float m0 = (float)( win8       & 1u);
                    float m1 = (float)((win8 >> 1) & 1u);
                    float m2 = (float)((win8 >> 2) & 1u);
                    float m3 = (float)((win8 >> 3) & 1u);
                    float m4 = (float)((win8 >> 4) & 1u);
                    float m5 = (float)((win8 >> 5) & 1u);
                    float m6 = (float)((win8 >> 6) & 1u);
                    float m7 = (float)((win8 >> 7) & 1u);
                    xa.x *= m0; xa.y *= m1; xb.x *= m2; xb.y *= m3;
                    xc.x *= m4; xc.y *= m5; xd.x *= m6; xd.y *= m7;
                    ya.x *= m0; ya.y *= m1; yb.x *= m2; yb.y *= m3;
                    yc.x *= m4; yc.y *= m5; yd.x *= m6; yd.y *= m7;
                }

                v2 xxa = xa * xa, xxb = xb * xb, xxc = xc * xc, xxd = xd * xd;
                v2 yya = ya * ya, yyb = yb * yb, yyc = yc * yc, yyd = yd * yd;
                v2 xya = xa * ya, xyb = xb * yb, xyc = xc * yc, xyd = xd * yd;

                float h;
                h = ((xa.x + xa.y) + (xb.x + xb.y)) + ((xc.x + xc.y) + xd.x);
                v2 hX  = { h, h + xd.y - xa.x };
                h = ((ya.x + ya.y) + (yb.x + yb.y)) + ((yc.x + yc.y) + yd.x);
                v2 hY  = { h, h + yd.y - ya.x };
                h = ((xxa.x + xxa.y) + (xxb.x + xxb.y)) + ((xxc.x + xxc.y) + xxd.x);
                v2 hXX = { h, h + xxd.y - xxa.x };
                h = ((yya.x + yya.y) + (yyb.x + yyb.y)) + ((yyc.x + yyc.y) + yyd.x);
                v2 hYY = { h, h + yyd.y - yya.x };
                h = ((xya.x + xya.y) + (xyb.x + xyb.y)) + ((xyc.x + xyc.y) + xyd.x);
                v2 hXY = { h, h + xyd.y - xya.x };

                v2 o;
                o = r0[ph]; r0[ph] = hX;  s0 += hX  - o;
                o = r1[ph]; r1[ph] = hY;  s1 += hY  - o;
                o = r2[ph]; r2[ph] = hXX; s2 += hXX - o;
                o = r3[ph]; r3[ph] = hYY; s3 += hYY - o;
                o = r4[ph]; r4[ph] = hXY; s4 += hXY - o;

                if (rr >= 6) {
                    v2 t3  = s0 * s1;
                    v2 t12 = s1 * s1 + s0 * s0;
                    v2 A1  = 2.0f * t3 + C1q;
                    v2 u   = 49.0f * s4 - t3;
                    v2 A2  = (2.0f * COVN) * u + C2q;
                    v2 B1  = t12 + C1q;
                    v2 w   = s2 + s3;
                    v2 vsum = 49.0f * w - t12;
                    v2 B2  = COVN * vsum + C2q;
                    v2 num = A1 * A2;
                    v2 den = B1 * B2;
                    float q0 = __builtin_amdgcn_rcpf(den.x);
                    float q1 = __builtin_amdgcn_rcpf(den.y);
                    lsum += num.x * q0 + num.y * q1;
                }

                // ---- rotate pipeline (renamed by 7-phase unroll) ----
                ax0 = bx0; ax1 = bx1; ax2 = bx2; ax3 = bx3;
                ay0 = by0; ay1 = by1; ay2 = by2; ay3 = by3;
                am0 = bm0; am1 = bm1;
                bx0 = tx0; bx1 = tx1; bx2 = tx2; bx3 = tx3;
                by0 = ty0; by1 = ty1; by2 = ty2; by3 = ty3;
                bm0 = tm0; bm1 = tm1;
            }
        }
    }

    // wave-level reduce (no LDS)
    #pragma unroll
    for (int off = 32; off > 0; off >>= 1) lsum += __shfl_down(lsum, off);
    if (tx == 0) {
        int flat = ((blockIdx.z * 14 + blockIdx.y * 2 + cz) * 3 + blockIdx.x);
        atomicAdd(&accum[flat & 1023], lsum);
    }
}

// ---- K4: finalize -> 1 - sum/N (double accumulate) ------------------------
__global__ void k_final(const float* __restrict__ accum, float* __restrict__ out) {
    __shared__ double sm[256];
    double v = 0.0;
    for (int i = threadIdx.x; i < 1024; i += 256) v += (double)accum[i];
    sm[threadIdx.x] = v;
    __syncthreads();
    #pragma unroll
    for (int off = 128; off > 0; off >>= 1) {
        if (threadIdx.x < off) sm[threadIdx.x] += sm[threadIdx.x + off];
        __syncthreads();
    }
    if (threadIdx.x == 0) {
        out[0] = (float)(1.0 - sm[0] / 18289152.0);   // N = 128*378*378
    }
}

extern "C" void kernel_launch(void* const* d_in, const int* in_sizes, int n_in,
                              void* d_out, int out_size, void* d_ws, size_t ws_size,
                              hipStream_t stream) {
    const float* X  = (const float*)d_in[0];
    const float* Y  = (const float*)d_in[1];
    const float* dr = (const float*)d_in[2];
    float* out = (float*)d_out;

    char* ws = (char*)d_ws;
    float* accum = (float*)ws;                        // 4 KB
    // maskB FIRST so k_ssim's +1-word mask over-read lands in bitsRaw (safe)
    u64* maskB = (u64*)(ws + 4096);                                  // 2.36 MB final mask
    u64* bitsRaw = (u64*)(ws + 4096 + (size_t)(BB * IMG_WORDS) * 8); // 2.36 MB binarized

    k_binarize<<<BIN_BLOCKS, 256, 0, stream>>>(Y, bitsRaw, accum);
    k_morph<<<BB * 8, 256, 0, stream>>>(bitsRaw, maskB);
    dim3 g(3, 7, 128);
    k_ssim<<<g, 128, 0, stream>>>(X, Y, dr, maskB, accum);
    k_final<<<1, 256, 0, stream>>>(accum, out);
}

// Round 7
// 214.785 us; speedup vs baseline: 3.3261x; 3.3261x over previous
//
#include <hip/hip_runtime.h>
#include <stdint.h>

typedef unsigned long long u64;
typedef float v2 __attribute__((ext_vector_type(2)));

#define THRESH_F 5e-5f
#define BB 128
#define HH 384
#define WW_ 384
#define WPR 6                        // u64 words per 384-pixel row
#define IMG_WORDS (HH*WPR)           // 2304
#define OH 378
#define OW 378
#define PIX (BB*HH*WW_)              // 18874368
#define COVN (49.0f/48.0f)

#define SLAB 48                      // output rows per morph block
#define HALO 30                      // morphology chain depth: 1 + 15 + 14
#define MAXROWS (SLAB + 2*HALO)      // 108
#define MAXW (MAXROWS * WPR)         // 648

#define BIN_BLOCKS 1536

// k_ssim geometry: 1-wave blocks, 7 chunks of 54 output rows (378 = 7*54).
// 2688 waves x 60 input rows: -10% total row work vs 5376x33 (halo 6/60 vs
// 6/33) and single residency generation (2688 <= 4096 capacity at VGPR 112).
#define CH_ROWS 54
#define IN_ROWS (CH_ROWS + 6)        // 60

// div by 6 via magic, valid for w < 131072
__device__ __forceinline__ int div6(int w) { return (w * 43691) >> 18; }

// ---- K1: binarize Y -> bits. MLP=8: 8 loads + 8 ballots per step ----------
__global__ void __launch_bounds__(256) k_binarize(const float* __restrict__ Y,
                                                  u64* __restrict__ bits,
                                                  float* __restrict__ accum) {
    if (blockIdx.x == 0) {           // zero accum bins (consumed by k_ssim)
        for (int i = threadIdx.x; i < 1024; i += 256) accum[i] = 0.f;
    }
    const int lane = threadIdx.x & 63;
    const int wave = (blockIdx.x * 256 + threadIdx.x) >> 6;   // global wave id
    const int nwaves = BIN_BLOCKS * 4;                        // 6144
    const int NSTEP = PIX / 512;                              // 36864
    for (int s = wave; s < NSTEP; s += nwaves) {
        size_t base = (size_t)s * 512 + lane;
        float a0 = Y[base];
        float a1 = Y[base + 64];
        float a2 = Y[base + 128];
        float a3 = Y[base + 192];
        float a4 = Y[base + 256];
        float a5 = Y[base + 320];
        float a6 = Y[base + 384];
        float a7 = Y[base + 448];
        u64 b0 = __ballot(a0 > THRESH_F);
        u64 b1 = __ballot(a1 > THRESH_F);
        u64 b2 = __ballot(a2 > THRESH_F);
        u64 b3 = __ballot(a3 > THRESH_F);
        u64 b4 = __ballot(a4 > THRESH_F);
        u64 b5 = __ballot(a5 > THRESH_F);
        u64 b6 = __ballot(a6 > THRESH_F);
        u64 b7 = __ballot(a7 > THRESH_F);
        if (lane < 8) {
            u64 lo = (lane == 0) ? b0 : (lane == 1) ? b1 : (lane == 2) ? b2 : b3;
            u64 hi = (lane == 4) ? b4 : (lane == 5) ? b5 : (lane == 6) ? b6 : b7;
            bits[(size_t)s * 8 + lane] = (lane < 4) ? lo : hi;
        }
    }
}

// ---- K2: fused morphology on bits, 8 slabs per image (1024 blocks) --------
__global__ void __launch_bounds__(256) k_morph(const u64* __restrict__ gbits,
                                               u64* __restrict__ gout_all) {
    __shared__ u64 A[MAXW];
    __shared__ u64 Bf[MAXW];
    const int blk = blockIdx.x;
    const int b = blk >> 3;
    const int slab = blk & 7;
    const int r0 = slab * SLAB;
    const int w0row = (r0 - HALO < 0) ? 0 : r0 - HALO;
    int w1row = r0 + SLAB + HALO; if (w1row > HH) w1row = HH;
    const int nrows = w1row - w0row;                  // 78 or 108
    const int NW = nrows * WPR;
    const int t = threadIdx.x;

    const u64* gin = gbits + (size_t)b * IMG_WORDS + (size_t)w0row * WPR;
    for (int w = t; w < NW; w += 256) A[w] = gin[w];
    __syncthreads();

    // ---- erode3: A -> Bf ----
    for (int w = t; w < NW; w += 256) {
        int row = div6(w);
        int ww = w - row * 6;
        int rlo = row > 0 ? row - 1 : row;
        int rhi = row < nrows - 1 ? row + 1 : row;
        u64 res = ~0ull;
        for (int rr = rlo; rr <= rhi; ++rr) {
            const u64* rp = &A[rr * 6];
            u64 a = ww > 0 ? rp[ww - 1] : 0ull;
            u64 bb = rp[ww];
            u64 c = ww < 5 ? rp[ww + 1] : 0ull;
            u64 l  = (bb << 1) | (ww > 0 ? (a >> 63) : 1ull);
            u64 r2 = (bb >> 1) | (ww < 5 ? (c << 63) : (1ull << 63));
            res &= bb & l & r2;
        }
        Bf[w] = res;
    }
    __syncthreads();

    // ---- dilate_h15: Bf -> A ----
    for (int w = t; w < NW; w += 256) {
        int row = div6(w);
        int ww = w - row * 6;
        const u64* rp = &Bf[row * 6];
        u64 a = ww > 0 ? rp[ww - 1] : 0ull;
        u64 bb = rp[ww];
        u64 c = ww < 5 ? rp[ww + 1] : 0ull;
        __uint128_t X = (((__uint128_t)bb) << 64) | a;
        X |= X << 1; X |= X << 2; X |= X << 4; X |= X << 8;
        __uint128_t Z = (((__uint128_t)c) << 64) | bb;
        Z |= Z >> 1; Z |= Z >> 2; Z |= Z >> 4; Z |= Z >> 8;
        A[w] = (u64)(X >> 64) | (u64)Z;
    }
    __syncthreads();

    // ---- dilate_v15: A -> Bf ----
    for (int w = t; w < NW; w += 256) {
        int row = div6(w);
        int ww = w - row * 6;
        int lo2 = row - 15 < 0 ? 0 : row - 15;
        int hi2 = row + 15 > nrows - 1 ? nrows - 1 : row + 15;
        u64 acc = 0ull;
        for (int rr = lo2; rr <= hi2; ++rr) acc |= A[rr * 6 + ww];
        Bf[w] = acc;
    }
    __syncthreads();

    // ---- erode_h14: Bf -> A ----
    for (int w = t; w < NW; w += 256) {
        int row = div6(w);
        int ww = w - row * 6;
        const u64* rp = &Bf[row * 6];
        u64 a = ww > 0 ? rp[ww - 1] : ~0ull;
        u64 bb = rp[ww];
        u64 c = ww < 5 ? rp[ww + 1] : ~0ull;
        u64 na = ~a, nb = ~bb, nc = ~c;
        __uint128_t X = (((__uint128_t)nb) << 64) | na;
        X |= X << 1; X |= X << 2; X |= X << 4; X |= X << 7;
        __uint128_t Z = (((__uint128_t)nc) << 64) | nb;
        Z |= Z >> 1; Z |= Z >> 2; Z |= Z >> 4; Z |= Z >> 7;
        A[w] = ~((u64)(X >> 64) | (u64)Z);
    }
    __syncthreads();

    // ---- erode_v14: A -> global, output rows [r0, r0+48) ----
    u64* gout = gout_all + (size_t)b * IMG_WORDS;
    const int base = r0 - w0row;
    for (int w = t; w < SLAB * WPR; w += 256) {
        int lrow = div6(w);
        int ww = w - lrow * 6;
        int lr = base + lrow;
        int lo2 = lr - 14 < 0 ? 0 : lr - 14;
        int hi2 = lr + 14 > nrows - 1 ? nrows - 1 : lr + 14;
        u64 acc = ~0ull;
        for (int rr = lo2; rr <= hi2; ++rr) acc &= A[rr * 6 + ww];
        gout[(size_t)(r0 + lrow) * WPR + ww] = acc;
    }
}

// ---- K3: masked SSIM, CW=2, DEPTH-2 row pipeline, 1-wave blocks -----------
// grid (3, 7, 128), block 64 (one wave). Each wave: chunk of 54 output rows
// (60 input rows). Inner body is the R1/R4-proven structure verbatim
// (VGPR 112, no spill): outer runtime bs loop + 7-phase unroll, prefetch
// unconditional with clamped row index. Plain launch_bounds(64) — NO
// min-waves arg (R6: the allocator's response is discontinuous, VGPR 48 +
// 1 GB of spill). No finalize fusion (R3/R5 both regressed).
__global__ void __launch_bounds__(64) k_ssim(
    const float* __restrict__ Xg, const float* __restrict__ Yg,
    const float* __restrict__ drg, const u64* __restrict__ Mg,
    float* __restrict__ accum)
{
    const int tx = threadIdx.x;                       // 0..63
    const int p  = blockIdx.x * 64 + tx;              // pair index
    const int chunk = blockIdx.y;                     // 0..6
    const int b  = blockIdx.z;

    float lsum = 0.0f;
    if (p < 189) {
        const int j  = p * 2;
        const int i0 = chunk * CH_ROWS;               // 378 = 7*54 exact
        const float drv = drg[b];
        const float C1q = 1e-4f * drv * drv * 2401.0f;    // C1*49^2
        const float C2q = 9e-4f * drv * drv * 2401.0f;    // C2*49^2
        const float* xr = Xg + (size_t)b * HH * WW_ + (size_t)i0 * WW_ + j;
        const float* yr = Yg + (size_t)b * HH * WW_ + (size_t)i0 * WW_ + j;
        const unsigned* mr = (const unsigned*)Mg + ((size_t)b * HH + i0) * 12 + (j >> 5);
        const int sh32 = j & 31;

        v2 r0[7], r1[7], r2[7], r3[7], r4[7];
        #pragma unroll
        for (int t = 0; t < 7; ++t) {
            r0[t] = 0.f; r1[t] = 0.f; r2[t] = 0.f; r3[t] = 0.f; r4[t] = 0.f;
        }
        v2 s0 = 0.f, s1 = 0.f, s2 = 0.f, s3 = 0.f, s4 = 0.f;

        // pipeline stage A (row rr), stage B (row rr+1)
        v2 ax0 = *(const v2*)(xr),     ax1 = *(const v2*)(xr + 2);
        v2 ax2 = *(const v2*)(xr + 4), ax3 = *(const v2*)(xr + 6);
        v2 ay0 = *(const v2*)(yr),     ay1 = *(const v2*)(yr + 2);
        v2 ay2 = *(const v2*)(yr + 4), ay3 = *(const v2*)(yr + 6);
        unsigned am0 = mr[0], am1 = mr[1];

        const float* xn1 = xr + WW_;
        const float* yn1 = yr + WW_;
        v2 bx0 = *(const v2*)(xn1),     bx1 = *(const v2*)(xn1 + 2);
        v2 bx2 = *(const v2*)(xn1 + 4), bx3 = *(const v2*)(xn1 + 6);
        v2 by0 = *(const v2*)(yn1),     by1 = *(const v2*)(yn1 + 2);
        v2 by2 = *(const v2*)(yn1 + 4), by3 = *(const v2*)(yn1 + 6);
        unsigned bm0 = mr[12], bm1 = mr[13];

        for (int bs = 0; bs < 63; bs += 7) {
            #pragma unroll
            for (int ph = 0; ph < 7; ++ph) {
                const int rr = bs + ph;
                if (rr >= IN_ROWS) break;             // uniform

                // ---- prefetch row min(rr+2, 59): unconditional, clamped ----
                int rp = rr + 2; if (rp > IN_ROWS - 1) rp = IN_ROWS - 1;
                const float* xn = xr + (size_t)rp * WW_;
                const float* yn = yr + (size_t)rp * WW_;
                v2 tx0 = *(const v2*)(xn),     tx1 = *(const v2*)(xn + 2);
                v2 tx2 = *(const v2*)(xn + 4), tx3 = *(const v2*)(xn + 6);
                v2 ty0 = *(const v2*)(yn),     ty1 = *(const v2*)(yn + 2);
                v2 ty2 = *(const v2*)(yn + 4), ty3 = *(const v2*)(yn + 6);
                const unsigned* mn = mr + (size_t)rp * 12;
                unsigned tm0 = mn[0], tm1 = mn[1];

                // ---- compute row rr from stage A ----
                unsigned win8 = __builtin_amdgcn_alignbit(am1, am0, sh32) & 0xFFu;
                v2 xa = ax0, xb = ax1, xc = ax2, xd = ax3;
                v2 ya = ay0, yb = ay1, yc = ay2, yd = ay3;

                if (__builtin_expect(__any(win8 != 0xFFu), 0)) {
                    float m0 = (float)( win8       & 1u);
                    float m1 = (float)((win8 >> 1) & 1u);
                    float m2 = (float)((win8 >> 2) & 1u);
                    float m3 = (float)((win8 >> 3) & 1u);
                    float m4 = (float)((win8 >> 4) & 1u);
                    float m5 = (float)((win8 >> 5) & 1u);
                    float m6 = (float)((win8 >> 6) & 1u);
                    float m7 = (float)((win8 >> 7) & 1u);
                    xa.x *= m0; xa.y *= m1; xb.x *= m2; xb.y *= m3;
                    xc.x *= m4; xc.y *= m5; xd.x *= m6; xd.y *= m7;
                    ya.x *= m0; ya.y *= m1; yb.x *= m2; yb.y *= m3;
                    yc.x *= m4; yc.y *= m5; yd.x *= m6; yd.y *= m7;
                }

                v2 xxa = xa * xa, xxb = xb * xb, xxc = xc * xc, xxd = xd * xd;
                v2 yya = ya * ya, yyb = yb * yb, yyc = yc * yc, yyd = yd * yd;
                v2 xya = xa * ya, xyb = xb * yb, xyc = xc * yc, xyd = xd * yd;

                float h;
                h = ((xa.x + xa.y) + (xb.x + xb.y)) + ((xc.x + xc.y) + xd.x);
                v2 hX  = { h, h + xd.y - xa.x };
                h = ((ya.x + ya.y) + (yb.x + yb.y)) + ((yc.x + yc.y) + yd.x);
                v2 hY  = { h, h + yd.y - ya.x };
                h = ((xxa.x + xxa.y) + (xxb.x + xxb.y)) + ((xxc.x + xxc.y) + xxd.x);
                v2 hXX = { h, h + xxd.y - xxa.x };
                h = ((yya.x + yya.y) + (yyb.x + yyb.y)) + ((yyc.x + yyc.y) + yyd.x);
                v2 hYY = { h, h + yyd.y - yya.x };
                h = ((xya.x + xya.y) + (xyb.x + xyb.y)) + ((xyc.x + xyc.y) + xyd.x);
                v2 hXY = { h, h + xyd.y - xya.x };

                v2 o;
                o = r0[ph]; r0[ph] = hX;  s0 += hX  - o;
                o = r1[ph]; r1[ph] = hY;  s1 += hY  - o;
                o = r2[ph]; r2[ph] = hXX; s2 += hXX - o;
                o = r3[ph]; r3[ph] = hYY; s3 += hYY - o;
                o = r4[ph]; r4[ph] = hXY; s4 += hXY - o;

                if (rr >= 6) {
                    v2 t3  = s0 * s1;
                    v2 t12 = s1 * s1 + s0 * s0;
                    v2 A1  = 2.0f * t3 + C1q;
                    v2 u   = 49.0f * s4 - t3;
                    v2 A2  = (2.0f * COVN) * u + C2q;
                    v2 B1  = t12 + C1q;
                    v2 w   = s2 + s3;
                    v2 vsum = 49.0f * w - t12;
                    v2 B2  = COVN * vsum + C2q;
                    v2 num = A1 * A2;
                    v2 den = B1 * B2;
                    float q0 = __builtin_amdgcn_rcpf(den.x);
                    float q1 = __builtin_amdgcn_rcpf(den.y);
                    lsum += num.x * q0 + num.y * q1;
                }

                // ---- rotate pipeline (renamed by 7-phase unroll) ----
                ax0 = bx0; ax1 = bx1; ax2 = bx2; ax3 = bx3;
                ay0 = by0; ay1 = by1; ay2 = by2; ay3 = by3;
                am0 = bm0; am1 = bm1;
                bx0 = tx0; bx1 = tx1; bx2 = tx2; bx3 = tx3;
                by0 = ty0; by1 = ty1; by2 = ty2; by3 = ty3;
                bm0 = tm0; bm1 = tm1;
            }
        }
    }

    // wave-level reduce (no LDS)
    #pragma unroll
    for (int off = 32; off > 0; off >>= 1) lsum += __shfl_down(lsum, off);
    if (tx == 0) {
        int flat = ((blockIdx.z * 7 + blockIdx.y) * 3 + blockIdx.x);
        atomicAdd(&accum[flat & 1023], lsum);
    }
}

// ---- K4: finalize -> 1 - sum/N (double accumulate) ------------------------
__global__ void k_final(const float* __restrict__ accum, float* __restrict__ out) {
    __shared__ double sm[256];
    double v = 0.0;
    for (int i = threadIdx.x; i < 1024; i += 256) v += (double)accum[i];
    sm[threadIdx.x] = v;
    __syncthreads();
    #pragma unroll
    for (int off = 128; off > 0; off >>= 1) {
        if (threadIdx.x < off) sm[threadIdx.x] += sm[threadIdx.x + off];
        __syncthreads();
    }
    if (threadIdx.x == 0) {
        out[0] = (float)(1.0 - sm[0] / 18289152.0);   // N = 128*378*378
    }
}

extern "C" void kernel_launch(void* const* d_in, const int* in_sizes, int n_in,
                              void* d_out, int out_size, void* d_ws, size_t ws_size,
                              hipStream_t stream) {
    const float* X  = (const float*)d_in[0];
    const float* Y  = (const float*)d_in[1];
    const float* dr = (const float*)d_in[2];
    float* out = (float*)d_out;

    char* ws = (char*)d_ws;
    float* accum = (float*)ws;                        // 4 KB
    // maskB FIRST so k_ssim's +1-word mask over-read lands in bitsRaw (safe)
    u64* maskB = (u64*)(ws + 4096);                                  // 2.36 MB final mask
    u64* bitsRaw = (u64*)(ws + 4096 + (size_t)(BB * IMG_WORDS) * 8); // 2.36 MB binarized

    k_binarize<<<BIN_BLOCKS, 256, 0, stream>>>(Y, bitsRaw, accum);
    k_morph<<<BB * 8, 256, 0, stream>>>(bitsRaw, maskB);
    dim3 g(3, 7, 128);
    k_ssim<<<g, 64, 0, stream>>>(X, Y, dr, maskB, accum);
    k_final<<<1, 256, 0, stream>>>(accum, out);
}